// Round 3
// baseline (320.859 us; speedup 1.0000x reference)
//
#include <hip/hip_runtime.h>

// DiffusionMLS: out[row[e]] += w[e]*(u[col[e]] - u[row[e]]), F=32 fp32.
// Round 3: CSR build with PACKED (col,w) payload -> one 8B scattered store
// per edge; cursor merged into next[] (copy of offsets) so fill does exactly
// one atomic + one 8B store per edge. Node-major gather, zero f32 atomics.

#define NFEAT 32
#define SCAN_TILE 2048   // 256 threads * 8 items

// ---------------- CSR build ----------------

__global__ __launch_bounds__(256) void hist_kernel(const int* __restrict__ row,
                                                   int* __restrict__ counts, int E) {
    int e = blockIdx.x * 256 + threadIdx.x;
    if (e < E) atomicAdd(&counts[row[e]], 1);
}

__global__ __launch_bounds__(256) void scan_block_kernel(const int* __restrict__ counts,
                                                         int* __restrict__ offsets,
                                                         int* __restrict__ partials, int N) {
    __shared__ int s[256];
    int tid = threadIdx.x;
    int base = blockIdx.x * SCAN_TILE + tid * 8;
    int v[8];
    int sum = 0;
#pragma unroll
    for (int j = 0; j < 8; ++j) {
        v[j] = (base + j < N) ? counts[base + j] : 0;
        sum += v[j];
    }
    s[tid] = sum;
    __syncthreads();
    for (int off = 1; off < 256; off <<= 1) {
        int t = (tid >= off) ? s[tid - off] : 0;
        __syncthreads();
        s[tid] += t;
        __syncthreads();
    }
    if (tid == 255) partials[blockIdx.x] = s[255];
    int run = s[tid] - sum;  // exclusive prefix of this thread's chunk
#pragma unroll
    for (int j = 0; j < 8; ++j) {
        if (base + j < N) offsets[base + j] = run;
        run += v[j];
    }
}

__global__ void scan_partials_kernel(int* partials, int nparts) {
    if (threadIdx.x == 0 && blockIdx.x == 0) {
        int run = 0;
        for (int i = 0; i < nparts; ++i) {
            int c = partials[i];
            partials[i] = run;
            run += c;
        }
    }
}

// offsets[i] += partials[block]; next[i] = offsets[i] (cursor seeded with base)
__global__ __launch_bounds__(256) void add_offsets_kernel(int* __restrict__ offsets,
                                                          int* __restrict__ next,
                                                          const int* __restrict__ partials,
                                                          int N) {
    int i = blockIdx.x * 256 + threadIdx.x;
    if (i < N) {
        int v = offsets[i] + partials[i >> 11];   // SCAN_TILE = 2048
        offsets[i] = v;
        next[i] = v;
    }
}

// one atomic + one packed 8B store per edge
__global__ __launch_bounds__(256) void fill_kernel(const int* __restrict__ row,
                                                   const int* __restrict__ col,
                                                   const float* __restrict__ w,
                                                   int* __restrict__ next,
                                                   uint2* __restrict__ csr, int E) {
    int e = blockIdx.x * 256 + threadIdx.x;
    if (e >= E) return;
    int r = row[e];
    uint2 p;
    p.x = (unsigned)col[e];
    p.y = __float_as_uint(w[e]);
    int pos = atomicAdd(&next[r], 1);
    csr[pos] = p;
}

// ---------------- node-major gather ----------------
// One wave per node. 8 edge-slots x 8 lanes; each lane owns one float4 (4 feats).

__global__ __launch_bounds__(256) void node_kernel(const float4* __restrict__ u4,
                                                   const int* __restrict__ offsets,
                                                   const int* __restrict__ counts,
                                                   const uint2* __restrict__ csr,
                                                   float4* __restrict__ out4, int N) {
    int node = (blockIdx.x * 256 + threadIdx.x) >> 6;
    if (node >= N) return;
    int lane = threadIdx.x & 63;
    int f4 = lane & 7;        // which float4 of the node's 8
    int slot = lane >> 3;     // edge slot 0..7

    int start = offsets[node];
    int cnt = counts[node];

    float4 acc = make_float4(0.f, 0.f, 0.f, 0.f);
    float wsum = 0.f;
    for (int i = start + slot; i < start + cnt; i += 8) {
        uint2 p = csr[i];
        int c = (int)p.x;
        float wt = __uint_as_float(p.y);
        float4 uc = u4[(size_t)c * 8 + f4];
        acc.x += wt * uc.x;
        acc.y += wt * uc.y;
        acc.z += wt * uc.z;
        acc.w += wt * uc.w;
        wsum += wt;
    }
    // reduce across the 8 slots (lane bits 3,4,5)
#pragma unroll
    for (int m = 8; m < 64; m <<= 1) {
        acc.x += __shfl_xor(acc.x, m, 64);
        acc.y += __shfl_xor(acc.y, m, 64);
        acc.z += __shfl_xor(acc.z, m, 64);
        acc.w += __shfl_xor(acc.w, m, 64);
        wsum  += __shfl_xor(wsum,  m, 64);
    }
    if (slot == 0) {
        float4 ur = u4[(size_t)node * 8 + f4];
        float4 o;
        o.x = acc.x - wsum * ur.x;
        o.y = acc.y - wsum * ur.y;
        o.z = acc.z - wsum * ur.z;
        o.w = acc.w - wsum * ur.w;
        out4[(size_t)node * 8 + f4] = o;
    }
}

// ---------------- fallback (atomic path, if ws too small) ----------------

__global__ __launch_bounds__(256) void zero_out_kernel(float* __restrict__ out, int n) {
    int i = blockIdx.x * blockDim.x + threadIdx.x;
    if (i < n) out[i] = 0.0f;
}

__global__ __launch_bounds__(256) void scatter_lap_kernel(const float4* __restrict__ u4,
                                                          const float* __restrict__ w,
                                                          const int* __restrict__ row,
                                                          const int* __restrict__ col,
                                                          float* __restrict__ out, int n_edges) {
    int tid = blockIdx.x * blockDim.x + threadIdx.x;
    int e = tid >> 3;
    int f4 = tid & 7;
    if (e >= n_edges) return;
    int r = row[e];
    int c = col[e];
    float wt = w[e];
    float4 uc = u4[(size_t)c * 8 + f4];
    float4 ur = u4[(size_t)r * 8 + f4];
    float* o = out + (size_t)r * NFEAT + f4 * 4;
    atomicAdd(o + 0, wt * (uc.x - ur.x));
    atomicAdd(o + 1, wt * (uc.y - ur.y));
    atomicAdd(o + 2, wt * (uc.z - ur.z));
    atomicAdd(o + 3, wt * (uc.w - ur.w));
}

extern "C" void kernel_launch(void* const* d_in, const int* in_sizes, int n_in,
                              void* d_out, int out_size, void* d_ws, size_t ws_size,
                              hipStream_t stream) {
    const float* u = (const float*)d_in[0];
    const float* w = (const float*)d_in[1];
    const int* ei = (const int*)d_in[2];  // [2, E] int32
    float* out = (float*)d_out;

    const int E = in_sizes[1];
    const int N = out_size / NFEAT;
    const int* row = ei;
    const int* col = ei + E;

    // workspace layout (256-B aligned regions)
    const size_t countsOff = 0;
    const size_t countsBytes = ((size_t)N * 4 + 255) & ~(size_t)255;
    const size_t offsetsOff = countsOff + countsBytes;
    const size_t nextOff = offsetsOff + countsBytes;
    const size_t partialsOff = nextOff + countsBytes;
    const size_t partialsBytes = 256;
    const size_t csrOff = partialsOff + partialsBytes;
    const size_t csrBytes = ((size_t)E * 8 + 255) & ~(size_t)255;
    const size_t totalWs = csrOff + csrBytes;

    if (ws_size < totalWs) {
        zero_out_kernel<<<(out_size + 255) / 256, 256, 0, stream>>>(out, out_size);
        long long threads_total = (long long)E * 8;
        scatter_lap_kernel<<<(unsigned)((threads_total + 255) / 256), 256, 0, stream>>>(
            (const float4*)u, w, row, col, out, E);
        return;
    }

    char* ws = (char*)d_ws;
    int* counts = (int*)(ws + countsOff);
    int* offsets = (int*)(ws + offsetsOff);
    int* next = (int*)(ws + nextOff);
    int* partials = (int*)(ws + partialsOff);
    uint2* csr = (uint2*)(ws + csrOff);

    // zero only counts (hist accumulates into it)
    hipMemsetAsync(counts, 0, (size_t)N * 4, stream);

    const int eBlocks = (E + 255) / 256;
    const int nScanBlocks = (N + SCAN_TILE - 1) / SCAN_TILE;

    hist_kernel<<<eBlocks, 256, 0, stream>>>(row, counts, E);
    scan_block_kernel<<<nScanBlocks, 256, 0, stream>>>(counts, offsets, partials, N);
    scan_partials_kernel<<<1, 64, 0, stream>>>(partials, nScanBlocks);
    add_offsets_kernel<<<(N + 255) / 256, 256, 0, stream>>>(offsets, next, partials, N);
    fill_kernel<<<eBlocks, 256, 0, stream>>>(row, col, w, next, csr, E);

    // one wave per node, 4 waves per block
    node_kernel<<<(N + 3) / 4, 256, 0, stream>>>((const float4*)u, offsets, counts,
                                                 csr, (float4*)out, N);
}

// Round 4
// 269.983 us; speedup vs baseline: 1.1884x; 1.1884x over previous
//
#include <hip/hip_runtime.h>

// DiffusionMLS: out[row[e]] += w[e]*(u[col[e]] - u[row[e]]), F=32 fp32.
// Round 4: (a) XCD-binned fill — blocks with blockIdx%8==b scatter only rows in
// node-range b, so each XCD's 1.6MB csr region stays in its own L2 and lines
// fill completely before writeback; (b) bf16 copy of u for the node-major
// gather (halves random gather bytes; u_bf16=6.4MB ~ L2-resident).

#define NFEAT 32
#define SCAN_TILE 2048   // 256 threads * 8 items
#define NBINS 8

// ---------------- u -> bf16 (RNE) ----------------
__global__ __launch_bounds__(256) void convert_u_kernel(const float4* __restrict__ u4,
                                                        ushort4* __restrict__ ub, int n4) {
    int i = blockIdx.x * 256 + threadIdx.x;
    if (i >= n4) return;
    float4 v = u4[i];
    ushort4 o;
    unsigned x;
    x = __float_as_uint(v.x); x += 0x7fffu + ((x >> 16) & 1u); o.x = (unsigned short)(x >> 16);
    x = __float_as_uint(v.y); x += 0x7fffu + ((x >> 16) & 1u); o.y = (unsigned short)(x >> 16);
    x = __float_as_uint(v.z); x += 0x7fffu + ((x >> 16) & 1u); o.z = (unsigned short)(x >> 16);
    x = __float_as_uint(v.w); x += 0x7fffu + ((x >> 16) & 1u); o.w = (unsigned short)(x >> 16);
    ub[i] = o;
}

// ---------------- CSR build ----------------

__global__ __launch_bounds__(256) void hist_kernel(const int* __restrict__ row,
                                                   int* __restrict__ counts, int E) {
    int e = blockIdx.x * 256 + threadIdx.x;
    if (e < E) atomicAdd(&counts[row[e]], 1);
}

__global__ __launch_bounds__(256) void scan_block_kernel(const int* __restrict__ counts,
                                                         int* __restrict__ offsets,
                                                         int* __restrict__ partials, int N) {
    __shared__ int s[256];
    int tid = threadIdx.x;
    int base = blockIdx.x * SCAN_TILE + tid * 8;
    int v[8];
    int sum = 0;
#pragma unroll
    for (int j = 0; j < 8; ++j) {
        v[j] = (base + j < N) ? counts[base + j] : 0;
        sum += v[j];
    }
    s[tid] = sum;
    __syncthreads();
    for (int off = 1; off < 256; off <<= 1) {
        int t = (tid >= off) ? s[tid - off] : 0;
        __syncthreads();
        s[tid] += t;
        __syncthreads();
    }
    if (tid == 255) partials[blockIdx.x] = s[255];
    int run = s[tid] - sum;
#pragma unroll
    for (int j = 0; j < 8; ++j) {
        if (base + j < N) offsets[base + j] = run;
        run += v[j];
    }
}

__global__ void scan_partials_kernel(int* partials, int nparts) {
    if (threadIdx.x == 0 && blockIdx.x == 0) {
        int run = 0;
        for (int i = 0; i < nparts; ++i) {
            int c = partials[i];
            partials[i] = run;
            run += c;
        }
    }
}

__global__ __launch_bounds__(256) void add_offsets_kernel(int* __restrict__ offsets,
                                                          int* __restrict__ next,
                                                          const int* __restrict__ partials,
                                                          int N) {
    int i = blockIdx.x * 256 + threadIdx.x;
    if (i < N) {
        int v = offsets[i] + partials[i >> 11];   // SCAN_TILE = 2048
        offsets[i] = v;
        next[i] = v;
    }
}

// XCD-binned fill: bin b handled by blocks with blockIdx%8==b (round-robin
// block->XCD dispatch keeps bin b's csr region hot in XCD b's L2).
__global__ __launch_bounds__(256) void fill_xcd_kernel(const int* __restrict__ row,
                                                       const int* __restrict__ col,
                                                       const float* __restrict__ w,
                                                       int* __restrict__ next,
                                                       uint2* __restrict__ csr,
                                                       int E, int binSize) {
    int bin = blockIdx.x & (NBINS - 1);
    int binBlock = blockIdx.x >> 3;
    int blocksInBin = gridDim.x >> 3;
    int binLo = bin * binSize;
    int binHi = binLo + binSize;
    int stride = blocksInBin * 256;
    for (int e = binBlock * 256 + threadIdx.x; e < E; e += stride) {
        int r = row[e];
        if (r >= binLo && r < binHi) {
            uint2 p;
            p.x = (unsigned)col[e];
            p.y = __float_as_uint(w[e]);
            int pos = atomicAdd(&next[r], 1);
            csr[pos] = p;
        }
    }
}

// ---------------- node-major gather (bf16 u for the random gathers) ----------------
// One wave per node. 8 edge-slots x 8 lanes; each lane owns 4 features.

__global__ __launch_bounds__(256) void node_bf16_kernel(const ushort4* __restrict__ ub,  // [N,8]
                                                        const float4* __restrict__ u4,  // [N,8] f32
                                                        const int* __restrict__ offsets,
                                                        const int* __restrict__ counts,
                                                        const uint2* __restrict__ csr,
                                                        float4* __restrict__ out4, int N) {
    int node = (blockIdx.x * 256 + threadIdx.x) >> 6;
    if (node >= N) return;
    int lane = threadIdx.x & 63;
    int f4 = lane & 7;
    int slot = lane >> 3;

    int start = offsets[node];
    int cnt = counts[node];

    float4 acc = make_float4(0.f, 0.f, 0.f, 0.f);
    float wsum = 0.f;
    for (int i = start + slot; i < start + cnt; i += 8) {
        uint2 p = csr[i];
        int c = (int)p.x;
        float wt = __uint_as_float(p.y);
        ushort4 us = ub[(size_t)c * 8 + f4];
        acc.x += wt * __uint_as_float((unsigned)us.x << 16);
        acc.y += wt * __uint_as_float((unsigned)us.y << 16);
        acc.z += wt * __uint_as_float((unsigned)us.z << 16);
        acc.w += wt * __uint_as_float((unsigned)us.w << 16);
        wsum += wt;
    }
#pragma unroll
    for (int m = 8; m < 64; m <<= 1) {
        acc.x += __shfl_xor(acc.x, m, 64);
        acc.y += __shfl_xor(acc.y, m, 64);
        acc.z += __shfl_xor(acc.z, m, 64);
        acc.w += __shfl_xor(acc.w, m, 64);
        wsum  += __shfl_xor(wsum,  m, 64);
    }
    if (slot == 0) {
        float4 ur = u4[(size_t)node * 8 + f4];   // f32 self-term (coalesced, exact)
        float4 o;
        o.x = acc.x - wsum * ur.x;
        o.y = acc.y - wsum * ur.y;
        o.z = acc.z - wsum * ur.z;
        o.w = acc.w - wsum * ur.w;
        out4[(size_t)node * 8 + f4] = o;
    }
}

// f32-gather variant (used if ws can't fit the bf16 copy)
__global__ __launch_bounds__(256) void node_kernel(const float4* __restrict__ u4,
                                                   const int* __restrict__ offsets,
                                                   const int* __restrict__ counts,
                                                   const uint2* __restrict__ csr,
                                                   float4* __restrict__ out4, int N) {
    int node = (blockIdx.x * 256 + threadIdx.x) >> 6;
    if (node >= N) return;
    int lane = threadIdx.x & 63;
    int f4 = lane & 7;
    int slot = lane >> 3;
    int start = offsets[node];
    int cnt = counts[node];
    float4 acc = make_float4(0.f, 0.f, 0.f, 0.f);
    float wsum = 0.f;
    for (int i = start + slot; i < start + cnt; i += 8) {
        uint2 p = csr[i];
        int c = (int)p.x;
        float wt = __uint_as_float(p.y);
        float4 uc = u4[(size_t)c * 8 + f4];
        acc.x += wt * uc.x;
        acc.y += wt * uc.y;
        acc.z += wt * uc.z;
        acc.w += wt * uc.w;
        wsum += wt;
    }
#pragma unroll
    for (int m = 8; m < 64; m <<= 1) {
        acc.x += __shfl_xor(acc.x, m, 64);
        acc.y += __shfl_xor(acc.y, m, 64);
        acc.z += __shfl_xor(acc.z, m, 64);
        acc.w += __shfl_xor(acc.w, m, 64);
        wsum  += __shfl_xor(wsum,  m, 64);
    }
    if (slot == 0) {
        float4 ur = u4[(size_t)node * 8 + f4];
        float4 o;
        o.x = acc.x - wsum * ur.x;
        o.y = acc.y - wsum * ur.y;
        o.z = acc.z - wsum * ur.z;
        o.w = acc.w - wsum * ur.w;
        out4[(size_t)node * 8 + f4] = o;
    }
}

// ---------------- fallback (atomic path, if ws too small) ----------------

__global__ __launch_bounds__(256) void zero_out_kernel(float* __restrict__ out, int n) {
    int i = blockIdx.x * blockDim.x + threadIdx.x;
    if (i < n) out[i] = 0.0f;
}

__global__ __launch_bounds__(256) void scatter_lap_kernel(const float4* __restrict__ u4,
                                                          const float* __restrict__ w,
                                                          const int* __restrict__ row,
                                                          const int* __restrict__ col,
                                                          float* __restrict__ out, int n_edges) {
    int tid = blockIdx.x * blockDim.x + threadIdx.x;
    int e = tid >> 3;
    int f4 = tid & 7;
    if (e >= n_edges) return;
    int r = row[e];
    int c = col[e];
    float wt = w[e];
    float4 uc = u4[(size_t)c * 8 + f4];
    float4 ur = u4[(size_t)r * 8 + f4];
    float* o = out + (size_t)r * NFEAT + f4 * 4;
    atomicAdd(o + 0, wt * (uc.x - ur.x));
    atomicAdd(o + 1, wt * (uc.y - ur.y));
    atomicAdd(o + 2, wt * (uc.z - ur.z));
    atomicAdd(o + 3, wt * (uc.w - ur.w));
}

extern "C" void kernel_launch(void* const* d_in, const int* in_sizes, int n_in,
                              void* d_out, int out_size, void* d_ws, size_t ws_size,
                              hipStream_t stream) {
    const float* u = (const float*)d_in[0];
    const float* w = (const float*)d_in[1];
    const int* ei = (const int*)d_in[2];  // [2, E] int32
    float* out = (float*)d_out;

    const int E = in_sizes[1];
    const int N = out_size / NFEAT;
    const int* row = ei;
    const int* col = ei + E;

    // workspace layout (256-B aligned regions)
    const size_t countsBytes = ((size_t)N * 4 + 255) & ~(size_t)255;
    const size_t countsOff = 0;
    const size_t offsetsOff = countsOff + countsBytes;
    const size_t nextOff = offsetsOff + countsBytes;
    const size_t partialsOff = nextOff + countsBytes;
    const size_t partialsBytes = 256;
    const size_t csrOff = partialsOff + partialsBytes;
    const size_t csrBytes = ((size_t)E * 8 + 255) & ~(size_t)255;
    const size_t ubOff = csrOff + csrBytes;
    const size_t ubBytes = ((size_t)N * NFEAT * 2 + 255) & ~(size_t)255;
    const size_t wsNoBf16 = ubOff;              // through csr
    const size_t wsFull = ubOff + ubBytes;      // + bf16 u copy

    if (ws_size < wsNoBf16) {
        zero_out_kernel<<<(out_size + 255) / 256, 256, 0, stream>>>(out, out_size);
        long long threads_total = (long long)E * 8;
        scatter_lap_kernel<<<(unsigned)((threads_total + 255) / 256), 256, 0, stream>>>(
            (const float4*)u, w, row, col, out, E);
        return;
    }

    char* ws = (char*)d_ws;
    int* counts = (int*)(ws + countsOff);
    int* offsets = (int*)(ws + offsetsOff);
    int* next = (int*)(ws + nextOff);
    int* partials = (int*)(ws + partialsOff);
    uint2* csr = (uint2*)(ws + csrOff);
    ushort4* ub = (ushort4*)(ws + ubOff);
    const bool useBf16 = (ws_size >= wsFull);

    hipMemsetAsync(counts, 0, (size_t)N * 4, stream);

    const int eBlocks = (E + 255) / 256;
    const int nScanBlocks = (N + SCAN_TILE - 1) / SCAN_TILE;

    if (useBf16) {
        int n4 = N * (NFEAT / 4);
        convert_u_kernel<<<(n4 + 255) / 256, 256, 0, stream>>>((const float4*)u, ub, n4);
    }

    hist_kernel<<<eBlocks, 256, 0, stream>>>(row, counts, E);
    scan_block_kernel<<<nScanBlocks, 256, 0, stream>>>(counts, offsets, partials, N);
    scan_partials_kernel<<<1, 64, 0, stream>>>(partials, nScanBlocks);
    add_offsets_kernel<<<(N + 255) / 256, 256, 0, stream>>>(offsets, next, partials, N);

    // XCD-binned fill: 8 bins x 128 blocks
    const int binSize = (N + NBINS - 1) / NBINS;
    fill_xcd_kernel<<<NBINS * 128, 256, 0, stream>>>(row, col, w, next, csr, E, binSize);

    if (useBf16) {
        node_bf16_kernel<<<(N + 3) / 4, 256, 0, stream>>>(ub, (const float4*)u, offsets,
                                                          counts, csr, (float4*)out, N);
    } else {
        node_kernel<<<(N + 3) / 4, 256, 0, stream>>>((const float4*)u, offsets, counts,
                                                     csr, (float4*)out, N);
    }
}